// Round 9
// baseline (118.731 us; speedup 1.0000x reference)
//
#include <hip/hip_runtime.h>

// Guided filter r=5, B=8 C=3 H=W=512 fp32 — single fused kernel, round 15.
// TY=32, 512-thread blocks (grid 8x16x24 = 3072, 2 blocks/CU).
// Rationale: vertical halo amortization — stat rows/output row 42/32=1.3125
// vs 26/16=1.625 at TY=16: P1 global loads -17%, P2a work -19% per output;
// P3/P4 per-output unchanged; barrier events halved. Static occupancy
// unchanged (2x8 = 16 waves/CU). All proven r13/r14 per-thread bodies kept:
//  - P1 19-row register window (38 loads in ONE VGPR batch; r11 lesson),
//    5 segs r0=9*seg (9/9/9/9/6 rows), single body with runtime row mask
//    (no intra-wave duplication; r12 lesson), trailing-product stash.
//  - P2a/P2b single body, runtime i<nout mask; INTR split block-uniform.
//  - P4 pair-split halves on wave-uniform tid<256 (template H=0/4).
// All LDS accesses affine (chunk starts multiple of 8: PB(c0+d)=PB(c0)+OFFD(d)).
// Pipeline: P1 vsums(x,y,xy,xx)->v4[42][97sw] f4 | P2a hsums+A,b->regs |
//   x-prefetch (512 thr, 1 f4 each) | P2b regs->ab2 (ALIASES v4, @0) |
//   P3 vsums(A,b) 4 segs x 8 rows ->vab @27,904 | P4 hsums+epilogue
//   (512 thr, 4 outputs each), 1x float4 store/thread.
// LDS 65,184 B (<= 64 KiB static cap) -> 2 blocks/CU.
// Aliasing safety: ab2 [0,27,888) and vab [27,904,49,152) both inside dead
// v4 footprint after the P2a-read-drain barrier; ab2/vab disjoint.
// Bank floors: strides unchanged (V4STR=97: row rot 4 banks; ABSTR=83:
// row rot 6 banks) — measured conflict counter is the multi-word access
// floor (b128 8 words/bank, b64 4/bank), not fixable conflicts.

#define R    5
#define TX   64
#define TY   32
#define IMG  512
#define AROWS (TY + 2 * R)   // 42
#define ACOLS (TX + 2 * R)   // 74
#define XCOLS (TX + 4 * R)   // 84
#define V4STR 97             // float4 row stride
#define ABSTR 83             // float2 row stride
#define OFF_VAB 27904                            // 218*128 >= ab2's 27,888
#define SMEM_TOTAL (AROWS * V4STR * 16)          // 65,184

#define PB(c)   ((c) + ((c) >> 3))
#define OFFD(d) ((d) + ((d) >> 3))   // PB(c0+d)-PB(c0) when c0%8==0

__device__ __forceinline__ float ccnt(int g) {
    int lo = max(g - R, 0), hi = min(g + R, IMG - 1);
    return (float)(hi - lo + 1);
}

// P2a inner: horizontal 11-sum ring + A,b math. Single body, runtime nout
// (per-lane mask — NO divergent body duplication). INTR is block-uniform.
template <bool INTR>
__device__ __forceinline__ void p2_body(const float4* __restrict__ bp,
                                        float2* pres, int nout, int ax0,
                                        float cy, bool ayok) {
    float4 ring[10];
#pragma unroll
    for (int d = 0; d < 10; ++d) ring[d] = bp[OFFD(d)];
    float sx = 0.f, sy = 0.f, sxy = 0.f, sxx = 0.f;
#pragma unroll
    for (int d = 0; d < 10; ++d) {
        sx += ring[d].x; sy += ring[d].y;
        sxy += ring[d].z; sxx += ring[d].w;
    }
#pragma unroll
    for (int i = 0; i < 10; ++i) {
        if (i < nout) {
            float4 lead = bp[OFFD(10 + i)];
            sx += lead.x; sy += lead.y; sxy += lead.z; sxx += lead.w;
            if (i > 0) {
                float4 o = ring[i - 1];
                sx -= o.x; sy -= o.y; sxy -= o.z; sxx -= o.w;
            }
            float A = 0.f, bb = 0.f;
            if (INTR) {
                const float inv = 1.0f / 121.0f;
                float mx = sx * inv, my = sy * inv;
                float cov = sxy * inv - mx * my;
                float var = sxx * inv - mx * mx;
                A = cov * __builtin_amdgcn_rcpf(var + 0.01f);
                bb = my - A * mx;
            } else {
                const int ax = ax0 + i;
                if (ayok && ((unsigned)ax < (unsigned)IMG)) {
                    float inv = __builtin_amdgcn_rcpf(cy * ccnt(ax));
                    float mx = sx * inv, my = sy * inv;
                    float cov = sxy * inv - mx * my;
                    float var = sxx * inv - mx * mx;
                    A = cov * __builtin_amdgcn_rcpf(var + 0.01f);
                    bb = my - A * mx;
                }
            }
            pres[i] = make_float2(A, bb);
        }
    }
}

// P4 half: 4 outputs (cols c0+H .. c0+H+3), ring cols d = H..H+13.
// H is a template const so all LDS offsets stay compile-time immediates.
template <int H, bool INTR>
__device__ __forceinline__ void p4_half(const float2* __restrict__ vb,
                                        const float4 xv4, float res[4],
                                        int gx0, float cy) {
    float2 ring[10];
#pragma unroll
    for (int d = 0; d < 10; ++d) ring[d] = vb[OFFD(H + d)];
    float sa = 0.f, sb = 0.f;
#pragma unroll
    for (int d = 0; d < 10; ++d) { sa += ring[d].x; sb += ring[d].y; }
    const float xv[4] = {xv4.x, xv4.y, xv4.z, xv4.w};
#pragma unroll
    for (int i = 0; i < 4; ++i) {
        float2 lead = vb[OFFD(H + 10 + i)];
        sa += lead.x; sb += lead.y;
        if (i > 0) {
            float2 o = ring[i - 1];
            sa -= o.x; sb -= o.y;
        }
        float inv;
        if (INTR) inv = 1.0f / 121.0f;
        else      inv = __builtin_amdgcn_rcpf(cy * ccnt(gx0 + i));
        res[i] = (sa * inv) * xv[i] + (sb * inv);
    }
}

__global__ __launch_bounds__(512, 4) void guided_fused(
        const float* __restrict__ x, const float* __restrict__ y,
        float* __restrict__ out) {
    __shared__ __align__(16) unsigned char smem[SMEM_TOTAL];
    float4 (*v4)[V4STR] = (float4(*)[V4STR])smem;
    float2 (*ab2)[ABSTR] = (float2(*)[ABSTR])smem;              // aliases v4
    float2 (*vab)[ABSTR] = (float2(*)[ABSTR])(smem + OFF_VAB);  // disjoint from ab2

    const int plane = blockIdx.z;
    const int tx0 = blockIdx.x * TX;
    const int ty0 = blockIdx.y * TY;
    const int tid = threadIdx.x;
    const size_t pbase = (size_t)plane * IMG * IMG;
    const float* xp = x + pbase;
    const float* yp = y + pbase;
    const bool interior = (tx0 >= 2 * R) && (tx0 + TX + 2 * R - 1 < IMG) &&
                          (ty0 >= 2 * R) && (ty0 + TY + 2 * R - 1 < IMG);

    // ---- P1: vertical 11-sums at 84 cols x 42 A,b-rows. 5 segs (9/9/9/9/6),
    // r0 = 9*seg; 19-row register window: 38 loads in one batch. Single body,
    // per-lane runtime mask r0+s<AROWS (seg4 stops at 6 rows).
    if (tid < 5 * XCOLS) {
        const int seg = tid / XCOLS;
        const int cc  = tid - seg * XCOLS;
        const int r0  = seg * 9;              // 0, 9, 18, 27, 36
        const int gx  = tx0 - 2 * R + cc;
        const int gy0 = ty0 - 2 * R + r0;

        float xv[19], yv[19];
        if (interior) {
            const float* xc = xp + (size_t)gy0 * IMG + gx;
            const float* yc = yp + (size_t)gy0 * IMG + gx;
#pragma unroll
            for (int j = 0; j < 19; ++j) {
                xv[j] = xc[(size_t)j * IMG];
                yv[j] = yc[(size_t)j * IMG];
            }
        } else {
            const bool xok = ((unsigned)gx < (unsigned)IMG);
            const bool rows_ok = (gy0 >= 0) && (gy0 + 18 < IMG);
            if (rows_ok) {
                if (xok) {
                    const float* xc = xp + (size_t)gy0 * IMG + gx;
                    const float* yc = yp + (size_t)gy0 * IMG + gx;
#pragma unroll
                    for (int j = 0; j < 19; ++j) {
                        xv[j] = xc[(size_t)j * IMG];
                        yv[j] = yc[(size_t)j * IMG];
                    }
                } else {
#pragma unroll
                    for (int j = 0; j < 19; ++j) { xv[j] = 0.f; yv[j] = 0.f; }
                }
            } else {
#pragma unroll
                for (int j = 0; j < 19; ++j) {
                    int gy = gy0 + j;
                    bool ok = xok && ((unsigned)gy < (unsigned)IMG);
                    size_t o = (size_t)gy * IMG + gx;
                    xv[j] = ok ? xp[o] : 0.f;
                    yv[j] = ok ? yp[o] : 0.f;
                }
            }
        }
        float sx = 0.f, sy = 0.f, sxy = 0.f, sxx = 0.f;
        float pxy[8], pxx[8];   // trailing-edge product stash (rows 0..7)
#pragma unroll
        for (int j = 0; j < 11; ++j) {
            float mxy = xv[j] * yv[j];
            float mxx = xv[j] * xv[j];
            sx += xv[j]; sy += yv[j];
            sxy += mxy; sxx += mxx;
            if (j < 8) { pxy[j] = mxy; pxx[j] = mxx; }
        }
        float4* wp = &v4[r0][PB(cc)];
        wp[0] = make_float4(sx, sy, sxy, sxx);
#pragma unroll
        for (int s = 1; s < 9; ++s) {
            if (r0 + s < AROWS) {   // seg4 stops at 6 rows
                float xn = xv[s + 10], yn = yv[s + 10];
                sx  += xn - xv[s - 1];
                sy  += yn - yv[s - 1];
                sxy += xn * yn - pxy[s - 1];
                sxx += xn * xn - pxx[s - 1];
                wp[(size_t)s * V4STR] = make_float4(sx, sy, sxy, sxx);
            }
        }
    }
    __syncthreads();

    // ---- P2a: horizontal 11-sums -> A,b on 74x42, DEFERRED to registers.
    // 378 threads: chunk ch = tid/42 (0..8), row r = tid%42, c0 = 8ch.
    // Runtime nout (8, or 10 for ch=8) masked per-lane inside ONE body.
    int p2_r = 0, p2_pb0 = 0, p2_nout = 0;
    float2 pres[10];
    if (tid < 9 * AROWS) {
        const int ch = tid / AROWS;
        const int r  = tid - ch * AROWS;
        const int nout = (ch == 8) ? 10 : 8;
        p2_r = r; p2_pb0 = 9 * ch; p2_nout = nout;
        const float4* bp = &v4[r][p2_pb0];
        const int ay = ty0 - R + r;
        const float cy = ccnt(ay);
        const bool ayok = ((unsigned)ay < (unsigned)IMG);
        const int ax0 = tx0 - R + 8 * ch;
        if (interior) p2_body<true >(bp, pres, nout, ax0, cy, ayok);
        else          p2_body<false>(bp, pres, nout, ax0, cy, ayok);
    }
    __syncthreads();   // all v4 reads drained -> safe to overwrite with ab2

    // ---- x-prefetch for P4 (2 phases ahead; L2 latency hides under P2b+P3).
    // 512 threads, ONE float4 each: t (t<256) covers chunk cols 0-3,
    // t+256 covers cols 4-7 of the same chunk.
    const int p4t  = tid & 255;
    const int p4oy = p4t >> 3;            // 0..31
    const int p4ch = p4t & 7;
    const int p4h  = (tid >> 8) * 4;      // 0 or 4, wave-uniform
    const size_t obase =
        (size_t)(ty0 + p4oy) * IMG + tx0 + 8 * p4ch + p4h;
    const float4 xv4 = *reinterpret_cast<const float4*>(&xp[obase]);

    // ---- P2b: write deferred A,b into ab2 (aliases v4 region). Affine,
    // single loop with runtime mask (no divergent duplication).
    if (tid < 9 * AROWS) {
        float2* bw = &ab2[p2_r][p2_pb0];
#pragma unroll
        for (int i = 0; i < 10; ++i) {
            if (i < p2_nout) bw[OFFD(i)] = pres[i];
        }
    }
    __syncthreads();

    // ---- P3: vertical 11-sums of (A,b): 74 cols x 4 segs of 8 rows. Ring.
    if (tid < 4 * ACOLS) {
        const int seg = tid / ACOLS;          // 0..3
        const int ac = tid - seg * ACOLS;
        const int r0 = seg * 8;
        const float2* rp = &ab2[r0][PB(ac)];
        float2* wp = &vab[r0][PB(ac)];
        float2 ring[10];
#pragma unroll
        for (int d = 0; d < 10; ++d) ring[d] = rp[(size_t)d * ABSTR];
        float sa = 0.f, sb = 0.f;
#pragma unroll
        for (int d = 0; d < 10; ++d) { sa += ring[d].x; sb += ring[d].y; }
#pragma unroll
        for (int s = 0; s < 8; ++s) {
            float2 lead = rp[(size_t)(10 + s) * ABSTR];
            sa += lead.x; sb += lead.y;
            if (s > 0) {
                float2 o = ring[s - 1];
                sa -= o.x; sb -= o.y;
            }
            wp[(size_t)s * ABSTR] = make_float2(sa, sb);
        }
    }
    __syncthreads();

    // ---- P4: horizontal 11-sums + epilogue. 512 threads: 32 rows x 8
    // chunks x 2 halves. Wave-uniform tid<256 split. Affine b64 reads;
    // prefetched x; 1x float4 store per thread.
    {
        const float2* vb = &vab[p4oy][9 * p4ch];   // PB(8ch) = 9ch
        const int gy = ty0 + p4oy;
        const int gx0 = tx0 + 8 * p4ch + p4h;
        float res[4];
        if (tid < 256) {
            if (interior) p4_half<0, true >(vb, xv4, res, gx0, 0.f);
            else          p4_half<0, false>(vb, xv4, res, gx0, ccnt(gy));
        } else {
            if (interior) p4_half<4, true >(vb, xv4, res, gx0, 0.f);
            else          p4_half<4, false>(vb, xv4, res, gx0, ccnt(gy));
        }
        *reinterpret_cast<float4*>(&out[pbase + obase]) =
            make_float4(res[0], res[1], res[2], res[3]);
    }
}

extern "C" void kernel_launch(void* const* d_in, const int* in_sizes, int n_in,
                              void* d_out, int out_size, void* d_ws, size_t ws_size,
                              hipStream_t stream) {
    const float* x = (const float*)d_in[0];
    const float* y = (const float*)d_in[1];
    float* out = (float*)d_out;

    const int planes = in_sizes[0] / (IMG * IMG);  // 24

    dim3 grid(IMG / TX, IMG / TY, planes);  // 8 x 16 x 24
    guided_fused<<<grid, 512, 0, stream>>>(x, y, out);
}